// Round 6
// baseline (746.912 us; speedup 1.0000x reference)
//
#include <hip/hip_runtime.h>
#include <hip/hip_bf16.h>
#include <stdint.h>

typedef __hip_bfloat16 bf16;
typedef __hip_bfloat162 bf162;

typedef __attribute__((ext_vector_type(8))) short short8;   // 8 bf16 = 4 VGPRs
typedef __attribute__((ext_vector_type(4))) float floatx4;  // MFMA accumulator

#define BSH   8        // bucket = 256 nodes
#define BSZ   256
#define CHUNK 8192     // edges per sort block
#define NBMAX 512      // max buckets supported (N <= 131072)
#define NSLAB 8        // feature slabs (= XCD count); slab = 16 feats = 32 B
#define NPW   4        // nodes per wave in agg

// Feature-sliced ("slab") layout for all bf16 feature matrices:
//   addr(node n, feature f) = slab(f>>4) * N * 16 + n * 16 + (f & 15)
// One slab = N x 32 B = 3.2 MB -> fits a single XCD's 4 MB L2.
// agg blocks pin slab = blockIdx.x % 8 (XCD round-robin): PROVEN round-5 --
// FETCH dropped 176 MB -> 55 MB (slab gathers are L2-resident).

// ---------------- helpers ----------------

__device__ __forceinline__ void acc2(float& a, float& b, unsigned u) {
    a += __uint_as_float(u << 16);
    b += __uint_as_float(u & 0xffff0000u);
}

// ---------------- prep + bhist (single dispatch) ----------------
// blocks [0, nCvt):        x (row-major f32) -> xbf (slab bf16)
// blocks [nCvt, nCvt+48):  weights -> B-fragment layout for mfma_f32_16x16x32_bf16
// blocks [nCvt+48, ...):   per-chunk bucket histogram of dst
__global__ __launch_bounds__(256)
void prep_bhist_kernel(const float* __restrict__ x, bf16* __restrict__ y, int n4, int nCvt,
                       const float* __restrict__ wr1, const float* __restrict__ wo1,
                       const float* __restrict__ wr2, const float* __restrict__ wo2,
                       const float* __restrict__ wr3, const float* __restrict__ wo3,
                       bf16* __restrict__ w1, bf16* __restrict__ w2, bf16* __restrict__ w3,
                       const int* __restrict__ dst, int* __restrict__ T,
                       int E, int NB, int GB) {
    __shared__ int lh[NBMAX];
    const int b = blockIdx.x;
    if (b < nCvt) {
        const int i = b * 256 + threadIdx.x;
        if (i < n4) {
            const int N = n4 >> 5;
            const int n = i >> 5;
            const int q = i & 31;          // features 4q..4q+3
            float4 v = ((const float4*)x)[i];
            union { bf16 bb[4]; unsigned long long u; } pk;
            pk.bb[0] = __float2bfloat16(v.x);
            pk.bb[1] = __float2bfloat16(v.y);
            pk.bb[2] = __float2bfloat16(v.z);
            pk.bb[3] = __float2bfloat16(v.w);
            *(unsigned long long*)(y + ((size_t)(q >> 2) * N + n) * 16 + (q & 3) * 4) = pk.u;
        }
        return;
    }
    if (b < nCvt + 48) {
        int t = (b - nCvt) * 256 + threadIdx.x;       // 0..12287
        const int layer = t >> 12;
        t &= 4095;
        const float* wrel  = (layer == 0) ? wr1 : (layer == 1) ? wr2 : wr3;
        const float* wroot = (layer == 0) ? wo1 : (layer == 1) ? wo2 : wo3;
        bf16*        wsw   = (layer == 0) ? w1  : (layer == 1) ? w2  : w3;
        const int lane = t & 63;
        const int ct   = (t >> 6) & 7;
        const int kt   = t >> 9;
        const int kbase = kt * 32 + (lane >> 4) * 8;
        const int n     = ct * 16 + (lane & 15);
        bf16* q = wsw + (size_t)t * 8;
#pragma unroll
        for (int j = 0; j < 8; ++j) {
            const int k = kbase + j;
            const float v = (k < 128) ? wrel[k * 128 + n] : wroot[(k - 128) * 128 + n];
            q[j] = __float2bfloat16(v);
        }
        return;
    }
    // ---- bhist ----
    const int bb = b - nCvt - 48;
    for (int u = threadIdx.x; u < NB; u += 256) lh[u] = 0;
    __syncthreads();
    const int beg = bb * CHUNK, end = min(beg + CHUNK, E);
    for (int e = beg + threadIdx.x; e < end; e += 256)
        atomicAdd(&lh[dst[e] >> BSH], 1);
    __syncthreads();
    for (int u = threadIdx.x; u < NB; u += 256)
        T[u * GB + bb] = lh[u];
}

// ---------------- CSR build: two-level counting sort ----------------

__global__ __launch_bounds__(256)
void scan1_kernel(const int* __restrict__ deg, int* __restrict__ rp,
                  int* __restrict__ bsum, int n) {
    __shared__ int s[256];
    const int tid = threadIdx.x;
    const int i = blockIdx.x * 256 + tid;
    const int d = (i < n) ? deg[i] : 0;
    s[tid] = d;
    __syncthreads();
    for (int off = 1; off < 256; off <<= 1) {
        int u = (tid >= off) ? s[tid - off] : 0;
        __syncthreads();
        s[tid] += u;
        __syncthreads();
    }
    if (i < n) rp[i] = s[tid] - d;
    if (tid == 255) bsum[blockIdx.x] = s[255];
}

__global__ __launch_bounds__(512)
void scan2_kernel(int* __restrict__ bsum, int G) {
    __shared__ int s[512];
    const int tid = threadIdx.x;
    const int d = (tid < G) ? bsum[tid] : 0;
    s[tid] = d;
    __syncthreads();
    for (int off = 1; off < 512; off <<= 1) {
        int u = (tid >= off) ? s[tid - off] : 0;
        __syncthreads();
        s[tid] += u;
        __syncthreads();
    }
    if (tid < G) bsum[tid] = s[tid] - d;
}

// scan3 folded into the two consumers: Tfinal[i] = T[i] + bsum[i >> 8]

__global__ __launch_bounds__(256)
void bscatter_kernel(const int* __restrict__ src, const int* __restrict__ dst,
                     const int* __restrict__ T, const int* __restrict__ bsum,
                     int* __restrict__ ebuf, int E, int NB, int GB) {
    __shared__ int lofs[NBMAX];
    const int b = blockIdx.x;
    for (int u = threadIdx.x; u < NB; u += 256) {
        const int idx = u * GB + b;
        lofs[u] = T[idx] + bsum[idx >> 8];
    }
    __syncthreads();
    const int beg = b * CHUNK, end = min(beg + CHUNK, E);
    for (int e = beg + threadIdx.x; e < end; e += 256) {
        const int d = dst[e];
        const int u = d >> BSH;
        const int pos = atomicAdd(&lofs[u], 1);
        ebuf[pos] = (src[e] << BSH) | (d & (BSZ - 1));
    }
}

__global__ __launch_bounds__(256)
void bbuild_kernel(const int* __restrict__ T, const int* __restrict__ bsum,
                   const int* __restrict__ ebuf,
                   int* __restrict__ rp, int* __restrict__ col,
                   int E, int N, int NB, int GB) {
    __shared__ int s[256];
    __shared__ int lrank[256];
    const int u = blockIdx.x;
    const int tid = threadIdx.x;
    const int i0 = u * GB;
    const int beg = T[i0] + bsum[i0 >> 8];
    const int i1 = (u + 1) * GB;
    const int end = (u + 1 < NB) ? (T[i1] + bsum[i1 >> 8]) : E;

    lrank[tid] = 0;
    __syncthreads();
    for (int e = beg + tid; e < end; e += 256)
        atomicAdd(&lrank[ebuf[e] & (BSZ - 1)], 1);
    __syncthreads();
    const int cntv = lrank[tid];
    s[tid] = cntv;
    __syncthreads();
    for (int off = 1; off < 256; off <<= 1) {
        int v = (tid >= off) ? s[tid - off] : 0;
        __syncthreads();
        s[tid] += v;
        __syncthreads();
    }
    const int excl = s[tid] - cntv;
    const int node = u * BSZ + tid;
    if (node < N) rp[node] = beg + excl;
    if (u == NB - 1 && tid == 0) rp[N] = E;
    lrank[tid] = beg + excl;
    __syncthreads();
    for (int e = beg + tid; e < end; e += 256) {
        const int p = ebuf[e];
        const int pos = atomicAdd(&lrank[p & (BSZ - 1)], 1);
        col[pos] = p >> BSH;
    }
}

// ---------------- aggregation (slab-sliced, XCD-pinned, wave-per-node) ----------------
// block: slab s = blockIdx.x % 8 (XCD round-robin), 8 waves x NPW nodes.
// WAVE-PER-NODE: the whole wave covers 16 edges per instruction
// (ep = lane>>2 edge slot, fl = lane&3 -> 8 B feature chunk). Edge-loop bound
// is wave-uniform -> no divergence (round-5's 4-lane-group version lockstepped
// on max(degree) of 16 groups, ~1.7x extra instrs). Tails: clamped+masked
// loads (touch only already-resident lines). 4-round shfl_xor folds the 16
// edge slots. Gather working set per XCD = its 3.2 MB slab -> L2-resident
// (round-5 proven: FETCH 176->55 MB). agg stored nontemporal.

__global__ __launch_bounds__(512)
void agg_kernel(const bf16* __restrict__ h, const int* __restrict__ rp,
                const int* __restrict__ col, bf16* __restrict__ agg, int N) {
    const int s    = blockIdx.x & 7;
    const int wid  = threadIdx.x >> 6;
    const int lane = threadIdx.x & 63;
    const int ep   = lane >> 2;          // edge slot 0..15
    const int fl   = lane & 3;           // 8 B feature chunk
    const bf16* Hs = h + (size_t)s * N * 16;
    bf16* As = agg + (size_t)s * N * 16;

    const int node0 = ((blockIdx.x >> 3) * 8 + wid) * NPW;

#pragma unroll 1
    for (int ni = 0; ni < NPW; ++ni) {
        const int node = node0 + ni;
        if (node >= N) return;
        const int beg = rp[node], end = rp[node + 1];
        float a0 = 0.f, a1 = 0.f, a2 = 0.f, a3 = 0.f;
        int e = beg;
        for (; e + 32 <= end; e += 32) {
            const int c0 = col[e + ep];
            const int c1 = col[e + 16 + ep];
            const uint2 r0 = *(const uint2*)(Hs + (size_t)c0 * 16 + fl * 4);
            const uint2 r1 = *(const uint2*)(Hs + (size_t)c1 * 16 + fl * 4);
            acc2(a0, a1, r0.x); acc2(a2, a3, r0.y);
            acc2(a0, a1, r1.x); acc2(a2, a3, r1.y);
        }
        if (e < end) {
            const int e0 = e + ep;
            const int c0 = col[(e0 < end) ? e0 : (end - 1)];
            const uint2 r0 = *(const uint2*)(Hs + (size_t)c0 * 16 + fl * 4);
            if (e0 < end) { acc2(a0, a1, r0.x); acc2(a2, a3, r0.y); }
            if (e + 16 < end) {
                const int e1 = e + 16 + ep;
                const int c1 = col[(e1 < end) ? e1 : (end - 1)];
                const uint2 r1 = *(const uint2*)(Hs + (size_t)c1 * 16 + fl * 4);
                if (e1 < end) { acc2(a0, a1, r1.x); acc2(a2, a3, r1.y); }
            }
        }
        // fold the 16 edge slots (lanes differing in bits 2..5)
#pragma unroll
        for (int m = 4; m <= 32; m <<= 1) {
            a0 += __shfl_xor(a0, m, 64);
            a1 += __shfl_xor(a1, m, 64);
            a2 += __shfl_xor(a2, m, 64);
            a3 += __shfl_xor(a3, m, 64);
        }
        if (lane < 4) {                  // lanes 0..3: ep==0, fl==lane
            union { bf16 bb[4]; unsigned long long u; } pk;
            pk.bb[0] = __float2bfloat16(a0);
            pk.bb[1] = __float2bfloat16(a1);
            pk.bb[2] = __float2bfloat16(a2);
            pk.bb[3] = __float2bfloat16(a3);
            __builtin_nontemporal_store(pk.u,
                (unsigned long long*)(As + (size_t)node * 16 + lane * 4));
        }
    }
}

// ---------------- MFMA dual GEMM: out = [agg|h] @ Wsw + b (+relu) ----------------
// 512 threads, 128 rows/block; wsw staged once in LDS; epilogue via LDS tile.
// A-fragments read from slab layout: feature k0..k0+7 lives at
//   (k0>>4)*N*16 + row*16 + (k0&15)   ((k0&15) in {0,8} -> 16 B aligned).
// bf16 epilogue writes slab layout; fp32 final epilogue writes row-major.

template <bool RELU, typename OT>
__global__ __launch_bounds__(512)
void mfma_gemm_kernel(const bf16* __restrict__ Aagg, const bf16* __restrict__ Hroot,
                      const bf16* __restrict__ wsw, const float* __restrict__ bias,
                      OT* __restrict__ out, int M) {
    __shared__ __align__(16) char smem[67584];
    const int tid = threadIdx.x;

    // stage all B-fragments (65536 B) into LDS: 512 thr x 16 B x 8
#pragma unroll
    for (int i = 0; i < 8; ++i) {
        const int off = i * 8192 + tid * 16;
        *(float4*)(smem + off) = *(const float4*)((const char*)wsw + off);
    }
    __syncthreads();

    const int lane = tid & 63;
    const int wave = tid >> 6;
    const int l15  = lane & 15;
    const int quad = lane >> 4;
    const int base = blockIdx.x * 128;
    const int row_a = base + wave * 16 + l15;
    const bool rowok = row_a < M;
    const bf16* wl = (const bf16*)smem;

    floatx4 acc[8];
#pragma unroll
    for (int ct = 0; ct < 8; ++ct) acc[ct] = (floatx4){0.f, 0.f, 0.f, 0.f};

#pragma unroll
    for (int kt = 0; kt < 8; ++kt) {
        const bf16* Abase = (kt < 4) ? Aagg : Hroot;
        const int k0 = (kt & 3) * 32 + quad * 8;
        short8 afrag = (short8){0, 0, 0, 0, 0, 0, 0, 0};
        if (rowok)
            afrag = *(const short8*)(Abase + ((size_t)(k0 >> 4) * M + row_a) * 16 + (k0 & 15));
#pragma unroll
        for (int ct = 0; ct < 8; ++ct) {
            const short8 bfrag = *(const short8*)(wl + (size_t)((kt * 8 + ct) * 64 + lane) * 8);
            acc[ct] = __builtin_amdgcn_mfma_f32_16x16x32_bf16(afrag, bfrag, acc[ct], 0, 0, 0);
        }
    }

    __syncthreads();   // all waves done reading wl -> reuse smem as output tile
    const int rloc = wave * 16 + quad * 4;

    if constexpr (sizeof(OT) == 2) {
        bf16* tl = (bf16*)smem;                // stride 136 bf16 = 272 B
#pragma unroll
        for (int ct = 0; ct < 8; ++ct) {
            const int colc = ct * 16 + l15;
            const float bv = bias[colc];
#pragma unroll
            for (int r = 0; r < 4; ++r) {
                float v = acc[ct][r] + bv;
                if (RELU) v = fmaxf(v, 0.f);
                tl[(rloc + r) * 136 + colc] = __float2bfloat16(v);
            }
        }
        __syncthreads();
        // slab-layout write: 8 slabs x 128 rows x 32 B = 2048 x 16 B chunks
#pragma unroll
        for (int i = 0; i < 4; ++i) {
            const int chunk = i * 512 + tid;
            const int slab = chunk >> 8;
            const int r    = (chunk >> 1) & 127;
            const int half = chunk & 1;
            if (base + r < M)
                *(float4*)((char*)out + ((size_t)slab * M + base + r) * 32 + half * 16) =
                    *(const float4*)(smem + r * 272 + slab * 32 + half * 16);
        }
    } else {
        float* tl = (float*)smem;              // stride 132 f32 = 528 B
#pragma unroll
        for (int ct = 0; ct < 8; ++ct) {
            const int colc = ct * 16 + l15;
            const float bv = bias[colc];
#pragma unroll
            for (int r = 0; r < 4; ++r) {
                float v = acc[ct][r] + bv;
                if (RELU) v = fmaxf(v, 0.f);
                tl[(rloc + r) * 132 + colc] = v;
            }
        }
        __syncthreads();
        // row-major fp32 out: 128 rows x 512 B
#pragma unroll
        for (int i = 0; i < 8; ++i) {
            const int chunk = i * 512 + tid;
            const int row = chunk >> 5;
            const int c   = chunk & 31;
            if (base + row < M)
                *(float4*)((char*)out + (size_t)(base + row) * 512 + c * 16) =
                    *(const float4*)(smem + row * 528 + c * 16);
        }
    }
}

// ---------------- launch ----------------

extern "C" void kernel_launch(void* const* d_in, const int* in_sizes, int n_in,
                              void* d_out, int out_size, void* d_ws, size_t ws_size,
                              hipStream_t stream) {
    const float* x       = (const float*)d_in[0];
    const int*   ei      = (const int*)d_in[1];
    const float* w_rel1  = (const float*)d_in[2];
    const float* w_root1 = (const float*)d_in[3];
    const float* b1      = (const float*)d_in[4];
    const float* w_rel2  = (const float*)d_in[5];
    const float* w_root2 = (const float*)d_in[6];
    const float* b2      = (const float*)d_in[7];
    const float* w_rel3  = (const float*)d_in[8];
    const float* w_root3 = (const float*)d_in[9];
    const float* b3      = (const float*)d_in[10];
    float* out = (float*)d_out;

    const int N = in_sizes[0] / 128;
    const int E = in_sizes[1] / 2;
    const int* src = ei;
    const int* dst = ei + E;

    // workspace layout (~84 MB)
    char* w = (char*)d_ws;
    auto alloc = [&](size_t bytes) {
        char* p = w;
        w += (bytes + 255) & ~(size_t)255;
        return p;
    };
    int*  col  = (int*)alloc((size_t)E * 4);            // 6.4 MB
    int*  rp   = (int*)alloc((size_t)(N + 1) * 4);      // 0.4 MB
    bf16* h1   = (bf16*)alloc((size_t)N * 128 * 2);     // 25.6 MB
    bf16* xbf  = (bf16*)alloc((size_t)N * 128 * 2);     // 25.6 MB (reused as h2)
    bf16* aggb = (bf16*)alloc((size_t)N * 128 * 2);     // 25.6 MB
    bf16* wsw1 = (bf16*)alloc(32768 * 2);               // 64 KB
    bf16* wsw2 = (bf16*)alloc(32768 * 2);
    bf16* wsw3 = (bf16*)alloc(32768 * 2);
    bf16* h2   = xbf;       // layer-2 output overwrites xbf (last read: layer-1 gemm)
    // CSR-build scratch aliases buffers written only AFTER the build completes:
    int*  T    = (int*)h1;                  // NB*GB ints (~306 KB) in h1's space
    int*  bsum = (int*)(h1 + 1024 * 1024);  // scan partials, past T
    int*  ebuf = (int*)aggb;                // E ints (6.4 MB) in aggb's space

    const int NB = (N + BSZ - 1) / BSZ;        // 391 buckets
    const int GB = (E + CHUNK - 1) / CHUNK;    // 196 sort blocks
    const int nT = NB * GB;                    // 76,636
    const int scanTBlocks = (nT + 255) / 256;  // 300 <= 512

    const int nodesPerBlk = 8 * NPW;                 // 8 waves x NPW nodes
    const int aggBlocks  = 8 * ((N + nodesPerBlk - 1) / nodesPerBlk);
    const int gemmBlocks = (N + 127) / 128;
    const int cvtBlocks  = (N * 32 + 255) / 256;

    // prep (cvt + wsw) and bhist: independent work, one dispatch
    prep_bhist_kernel<<<cvtBlocks + 48 + GB, 256, 0, stream>>>(
        x, xbf, N * 32, cvtBlocks,
        w_rel1, w_root1, w_rel2, w_root2, w_rel3, w_root3,
        wsw1, wsw2, wsw3,
        dst, T, E, NB, GB);

    // CSR by dst: two-level counting sort (scan3 folded into consumers)
    scan1_kernel<<<scanTBlocks, 256, 0, stream>>>(T, T, bsum, nT);
    scan2_kernel<<<1, 512, 0, stream>>>(bsum, scanTBlocks);
    bscatter_kernel<<<GB, 256, 0, stream>>>(src, dst, T, bsum, ebuf, E, NB, GB);
    bbuild_kernel<<<NB, 256, 0, stream>>>(T, bsum, ebuf, rp, col, E, N, NB, GB);

    // layer 1
    agg_kernel<<<aggBlocks, 512, 0, stream>>>(xbf, rp, col, aggb, N);
    mfma_gemm_kernel<true, bf16><<<gemmBlocks, 512, 0, stream>>>(aggb, xbf, wsw1, b1, h1, N);
    // layer 2
    agg_kernel<<<aggBlocks, 512, 0, stream>>>(h1, rp, col, aggb, N);
    mfma_gemm_kernel<true, bf16><<<gemmBlocks, 512, 0, stream>>>(aggb, h1, wsw2, b2, h2, N);
    // layer 3
    agg_kernel<<<aggBlocks, 512, 0, stream>>>(h2, rp, col, aggb, N);
    mfma_gemm_kernel<false, float><<<gemmBlocks, 512, 0, stream>>>(aggb, h2, wsw3, b3, out, N);
}

// Round 7
// 429.992 us; speedup vs baseline: 1.7370x; 1.7370x over previous
//
#include <hip/hip_runtime.h>
#include <hip/hip_bf16.h>
#include <stdint.h>

typedef __hip_bfloat16 bf16;
typedef __hip_bfloat162 bf162;

typedef __attribute__((ext_vector_type(8))) short short8;   // 8 bf16 = 4 VGPRs
typedef __attribute__((ext_vector_type(4))) float floatx4;  // MFMA accumulator

#define BSH   8        // bucket = 256 nodes
#define BSZ   256
#define CHUNK 8192     // edges per sort block
#define NBMAX 512      // max buckets supported (N <= 131072)

// ---------------- XCD producer->consumer alignment ----------------
// gemm block g (rows 128g..128g+127) runs on XCD g%8 (bid round-robin).
// agg/cvt handle 8-node chunks; chunk c corresponds to (g = c/16, off = (c%16)*8).
// We assign chunk c to a block whose bid%8 == g%8 so the XCD that WRITES
// aggb/xbf rows is the XCD whose gemm block READS them (L2-local, no
// cross-XCD flush+refetch). Bijection: bid = 8*i + x, x = bid&7;
// g = x + 8*(i>>4), off = (i&15)*8  ->  node0 = g*128 + off.
__device__ __forceinline__ int swz_node0(int bid) {
    const int x = bid & 7;
    const int i = bid >> 3;
    return (x + 8 * (i >> 4)) * 128 + (i & 15) * 8;
}

// ---------------- helpers ----------------

__device__ __forceinline__ void acc2(float& a, float& b, unsigned u) {
    a += __uint_as_float(u << 16);
    b += __uint_as_float(u & 0xffff0000u);
}

// ---------------- prep + bhist (single dispatch) ----------------
// blocks [0, nCvt):        x (row-major f32) -> xbf (row-major bf16), XCD-swizzled chunks
// blocks [nCvt, nCvt+48):  weights -> B-fragment layout for mfma_f32_16x16x32_bf16:
//   wsw[((kt*8+ct)*64+lane)*8 + j] = W[kt*32 + (lane>>4)*8 + j][ct*16 + (lane&15)]
//   where W = concat_k(w_rel, w_root), 256x128 row-major.
// blocks [nCvt+48, ...):   per-chunk bucket histogram of dst
__global__ __launch_bounds__(256)
void prep_bhist_kernel(const float* __restrict__ x, bf16* __restrict__ y, int N, int nCvt,
                       const float* __restrict__ wr1, const float* __restrict__ wo1,
                       const float* __restrict__ wr2, const float* __restrict__ wo2,
                       const float* __restrict__ wr3, const float* __restrict__ wo3,
                       bf16* __restrict__ w1, bf16* __restrict__ w2, bf16* __restrict__ w3,
                       const int* __restrict__ dst, int* __restrict__ T,
                       int E, int NB, int GB) {
    __shared__ int lh[NBMAX];
    const int b = blockIdx.x;
    if (b < nCvt) {
        const int node = swz_node0(b) + (threadIdx.x >> 5);
        if (node < N) {
            const int q = threadIdx.x & 31;        // float4 index within row
            const int i = node * 32 + q;
            float4 v = ((const float4*)x)[i];
            bf162 a, c;
            a.x = __float2bfloat16(v.x); a.y = __float2bfloat16(v.y);
            c.x = __float2bfloat16(v.z); c.y = __float2bfloat16(v.w);
            ((bf162*)y)[i * 2]     = a;
            ((bf162*)y)[i * 2 + 1] = c;
        }
        return;
    }
    if (b < nCvt + 48) {
        int t = (b - nCvt) * 256 + threadIdx.x;       // 0..12287
        const int layer = t >> 12;
        t &= 4095;
        const float* wrel  = (layer == 0) ? wr1 : (layer == 1) ? wr2 : wr3;
        const float* wroot = (layer == 0) ? wo1 : (layer == 1) ? wo2 : wo3;
        bf16*        wsw   = (layer == 0) ? w1  : (layer == 1) ? w2  : w3;
        const int lane = t & 63;
        const int ct   = (t >> 6) & 7;
        const int kt   = t >> 9;
        const int kbase = kt * 32 + (lane >> 4) * 8;
        const int n     = ct * 16 + (lane & 15);
        bf16* q = wsw + (size_t)t * 8;
#pragma unroll
        for (int j = 0; j < 8; ++j) {
            const int k = kbase + j;
            const float v = (k < 128) ? wrel[k * 128 + n] : wroot[(k - 128) * 128 + n];
            q[j] = __float2bfloat16(v);
        }
        return;
    }
    // ---- bhist ----
    const int bb = b - nCvt - 48;
    for (int u = threadIdx.x; u < NB; u += 256) lh[u] = 0;
    __syncthreads();
    const int beg = bb * CHUNK, end = min(beg + CHUNK, E);
    for (int e = beg + threadIdx.x; e < end; e += 256)
        atomicAdd(&lh[dst[e] >> BSH], 1);
    __syncthreads();
    for (int u = threadIdx.x; u < NB; u += 256)
        T[u * GB + bb] = lh[u];
}

// ---------------- CSR build: two-level counting sort ----------------

__global__ __launch_bounds__(256)
void scan1_kernel(const int* __restrict__ deg, int* __restrict__ rp,
                  int* __restrict__ bsum, int n) {
    __shared__ int s[256];
    const int tid = threadIdx.x;
    const int i = blockIdx.x * 256 + tid;
    const int d = (i < n) ? deg[i] : 0;
    s[tid] = d;
    __syncthreads();
    for (int off = 1; off < 256; off <<= 1) {
        int u = (tid >= off) ? s[tid - off] : 0;
        __syncthreads();
        s[tid] += u;
        __syncthreads();
    }
    if (i < n) rp[i] = s[tid] - d;
    if (tid == 255) bsum[blockIdx.x] = s[255];
}

__global__ __launch_bounds__(512)
void scan2_kernel(int* __restrict__ bsum, int G) {
    __shared__ int s[512];
    const int tid = threadIdx.x;
    const int d = (tid < G) ? bsum[tid] : 0;
    s[tid] = d;
    __syncthreads();
    for (int off = 1; off < 512; off <<= 1) {
        int u = (tid >= off) ? s[tid - off] : 0;
        __syncthreads();
        s[tid] += u;
        __syncthreads();
    }
    if (tid < G) bsum[tid] = s[tid] - d;
}

// scan3 folded into the two consumers: Tfinal[i] = T[i] + bsum[i >> 8]

__global__ __launch_bounds__(256)
void bscatter_kernel(const int* __restrict__ src, const int* __restrict__ dst,
                     const int* __restrict__ T, const int* __restrict__ bsum,
                     int* __restrict__ ebuf, int E, int NB, int GB) {
    __shared__ int lofs[NBMAX];
    const int b = blockIdx.x;
    for (int u = threadIdx.x; u < NB; u += 256) {
        const int idx = u * GB + b;
        lofs[u] = T[idx] + bsum[idx >> 8];
    }
    __syncthreads();
    const int beg = b * CHUNK, end = min(beg + CHUNK, E);
    for (int e = beg + threadIdx.x; e < end; e += 256) {
        const int d = dst[e];
        const int u = d >> BSH;
        const int pos = atomicAdd(&lofs[u], 1);
        ebuf[pos] = (src[e] << BSH) | (d & (BSZ - 1));
    }
}

__global__ __launch_bounds__(256)
void bbuild_kernel(const int* __restrict__ T, const int* __restrict__ bsum,
                   const int* __restrict__ ebuf,
                   int* __restrict__ rp, int* __restrict__ col,
                   int E, int N, int NB, int GB) {
    __shared__ int s[256];
    __shared__ int lrank[256];
    const int u = blockIdx.x;
    const int tid = threadIdx.x;
    const int i0 = u * GB;
    const int beg = T[i0] + bsum[i0 >> 8];
    const int i1 = (u + 1) * GB;
    const int end = (u + 1 < NB) ? (T[i1] + bsum[i1 >> 8]) : E;

    lrank[tid] = 0;
    __syncthreads();
    for (int e = beg + tid; e < end; e += 256)
        atomicAdd(&lrank[ebuf[e] & (BSZ - 1)], 1);
    __syncthreads();
    const int cntv = lrank[tid];
    s[tid] = cntv;
    __syncthreads();
    for (int off = 1; off < 256; off <<= 1) {
        int v = (tid >= off) ? s[tid - off] : 0;
        __syncthreads();
        s[tid] += v;
        __syncthreads();
    }
    const int excl = s[tid] - cntv;
    const int node = u * BSZ + tid;
    if (node < N) rp[node] = beg + excl;
    if (u == NB - 1 && tid == 0) rp[N] = E;
    lrank[tid] = beg + excl;
    __syncthreads();
    for (int e = beg + tid; e < end; e += 256) {
        const int p = ebuf[e];
        const int pos = atomicAdd(&lrank[p & (BSZ - 1)], 1);
        col[pos] = p >> BSH;
    }
}

// ---------------- aggregation (CSR, atomic-free, bf16, row-major) ----------------
// PROVEN 64 us / 176 MB (gather service-rate-bound; instruction A/Bs r0/r2 flat).
// one wave per node; lanes 0-31 own features l32*4..+3 of even edges, lanes
// 32-63 of odd edges; dwordx2 per lane = 2 rows/instruction; shfl_xor(32) combine.
// NEW: node chunks XCD-swizzled so this block's aggb writes land in the L2 of
// the XCD whose gemm block will read them.

__global__ __launch_bounds__(512)
void agg_kernel(const bf16* __restrict__ h, const int* __restrict__ rp,
                const int* __restrict__ col, bf16* __restrict__ agg, int N) {
    const int lane = threadIdx.x & 63;
    const int wid  = threadIdx.x >> 6;
    const int node = swz_node0(blockIdx.x) + wid;
    if (node >= N) return;
    const int half = lane >> 5;
    const int l32  = lane & 31;
    const int f    = l32 * 4;
    const int beg = rp[node], end = rp[node + 1];

    float acc[4] = {0.f, 0.f, 0.f, 0.f};
    int e = beg;
#pragma unroll 2
    for (; e + 8 <= end; e += 8) {
        const int s0 = col[e + half];
        const int s1 = col[e + 2 + half];
        const int s2 = col[e + 4 + half];
        const int s3 = col[e + 6 + half];
        const uint2 r0 = *(const uint2*)(h + (size_t)s0 * 128 + f);
        const uint2 r1 = *(const uint2*)(h + (size_t)s1 * 128 + f);
        const uint2 r2 = *(const uint2*)(h + (size_t)s2 * 128 + f);
        const uint2 r3 = *(const uint2*)(h + (size_t)s3 * 128 + f);
        acc2(acc[0], acc[1], r0.x); acc2(acc[2], acc[3], r0.y);
        acc2(acc[0], acc[1], r1.x); acc2(acc[2], acc[3], r1.y);
        acc2(acc[0], acc[1], r2.x); acc2(acc[2], acc[3], r2.y);
        acc2(acc[0], acc[1], r3.x); acc2(acc[2], acc[3], r3.y);
    }
    for (; e < end; e += 2) {
        const bool act = (e + half) < end;
        const int s = col[act ? (e + half) : e];
        const uint2 r = *(const uint2*)(h + (size_t)s * 128 + f);
        if (act) { acc2(acc[0], acc[1], r.x); acc2(acc[2], acc[3], r.y); }
    }
#pragma unroll
    for (int j = 0; j < 4; ++j)
        acc[j] += __shfl_xor(acc[j], 32, 64);
    if (half == 0) {
        bf162 o0, o1;
        o0.x = __float2bfloat16(acc[0]); o0.y = __float2bfloat16(acc[1]);
        o1.x = __float2bfloat16(acc[2]); o1.y = __float2bfloat16(acc[3]);
        bf162* q = (bf162*)(agg + (size_t)node * 128 + f);
        q[0] = o0;
        q[1] = o1;
    }
}

// ---------------- MFMA dual GEMM: out = [agg|h] @ Wsw + b (+relu) ----------------
// 512 threads, 128 rows/block; wsw staged once in LDS; epilogue via LDS tile
// (kills scattered 2-B stores). aggb read is XCD-local thanks to agg swizzle;
// h root-half is XCD-local for free (same gemm grid wrote it).
// __launch_bounds__(512,4): cap VGPR so LDS (66 KB) stays the only occupancy
// limit -> 2 blocks/CU, 16 waves/CU.

template <bool RELU, typename OT>
__global__ __launch_bounds__(512, 4)
void mfma_gemm_kernel(const bf16* __restrict__ Aagg, const bf16* __restrict__ Hroot,
                      const bf16* __restrict__ wsw, const float* __restrict__ bias,
                      OT* __restrict__ out, int M) {
    __shared__ __align__(16) char smem[67584];
    const int tid = threadIdx.x;

    // stage all B-fragments (65536 B) into LDS: 512 thr x 16 B x 8
#pragma unroll
    for (int i = 0; i < 8; ++i) {
        const int off = i * 8192 + tid * 16;
        *(float4*)(smem + off) = *(const float4*)((const char*)wsw + off);
    }
    __syncthreads();

    const int lane = tid & 63;
    const int wave = tid >> 6;
    const int l15  = lane & 15;
    const int quad = lane >> 4;
    const int base = blockIdx.x * 128;
    const int row_a = base + wave * 16 + l15;
    const bool rowok = row_a < M;
    const bf16* wl = (const bf16*)smem;

    floatx4 acc[8];
#pragma unroll
    for (int ct = 0; ct < 8; ++ct) acc[ct] = (floatx4){0.f, 0.f, 0.f, 0.f};

#pragma unroll
    for (int kt = 0; kt < 8; ++kt) {
        const bf16* Abase = (kt < 4) ? Aagg : Hroot;
        const int k0 = (kt & 3) * 32 + quad * 8;
        short8 afrag = (short8){0, 0, 0, 0, 0, 0, 0, 0};
        if (rowok) afrag = *(const short8*)(Abase + (size_t)row_a * 128 + k0);
#pragma unroll
        for (int ct = 0; ct < 8; ++ct) {
            const short8 bfrag = *(const short8*)(wl + (size_t)((kt * 8 + ct) * 64 + lane) * 8);
            acc[ct] = __builtin_amdgcn_mfma_f32_16x16x32_bf16(afrag, bfrag, acc[ct], 0, 0, 0);
        }
    }

    __syncthreads();   // all waves done reading wl -> reuse smem as output tile
    const int rloc = wave * 16 + quad * 4;

    if constexpr (sizeof(OT) == 2) {
        bf16* tl = (bf16*)smem;                // stride 136 bf16 = 272 B (16-aligned)
#pragma unroll
        for (int ct = 0; ct < 8; ++ct) {
            const int colc = ct * 16 + l15;
            const float bv = bias[colc];
#pragma unroll
            for (int r = 0; r < 4; ++r) {
                float v = acc[ct][r] + bv;
                if (RELU) v = fmaxf(v, 0.f);
                tl[(rloc + r) * 136 + colc] = __float2bfloat16(v);
            }
        }
        __syncthreads();
        // 128 rows x 256 B out, coalesced dwordx4: 2048 chunks / 512 thr
#pragma unroll
        for (int i = 0; i < 4; ++i) {
            const int chunk = i * 512 + tid;
            const int row = chunk >> 4;
            const int c   = chunk & 15;
            if (base + row < M)
                *(float4*)((char*)out + (size_t)(base + row) * 256 + c * 16) =
                    *(const float4*)(smem + row * 272 + c * 16);
        }
    } else {
        float* tl = (float*)smem;              // stride 132 f32 = 528 B (16-aligned)
#pragma unroll
        for (int ct = 0; ct < 8; ++ct) {
            const int colc = ct * 16 + l15;
            const float bv = bias[colc];
#pragma unroll
            for (int r = 0; r < 4; ++r) {
                float v = acc[ct][r] + bv;
                if (RELU) v = fmaxf(v, 0.f);
                tl[(rloc + r) * 132 + colc] = v;
            }
        }
        __syncthreads();
        // 128 rows x 512 B out: 4096 chunks / 512 thr
#pragma unroll
        for (int i = 0; i < 8; ++i) {
            const int chunk = i * 512 + tid;
            const int row = chunk >> 5;
            const int c   = chunk & 31;
            if (base + row < M)
                *(float4*)((char*)out + (size_t)(base + row) * 512 + c * 16) =
                    *(const float4*)(smem + row * 528 + c * 16);
        }
    }
}

// ---------------- launch ----------------

extern "C" void kernel_launch(void* const* d_in, const int* in_sizes, int n_in,
                              void* d_out, int out_size, void* d_ws, size_t ws_size,
                              hipStream_t stream) {
    const float* x       = (const float*)d_in[0];
    const int*   ei      = (const int*)d_in[1];
    const float* w_rel1  = (const float*)d_in[2];
    const float* w_root1 = (const float*)d_in[3];
    const float* b1      = (const float*)d_in[4];
    const float* w_rel2  = (const float*)d_in[5];
    const float* w_root2 = (const float*)d_in[6];
    const float* b2      = (const float*)d_in[7];
    const float* w_rel3  = (const float*)d_in[8];
    const float* w_root3 = (const float*)d_in[9];
    const float* b3      = (const float*)d_in[10];
    float* out = (float*)d_out;

    const int N = in_sizes[0] / 128;
    const int E = in_sizes[1] / 2;
    const int* src = ei;
    const int* dst = ei + E;

    // workspace layout (~84 MB)
    char* w = (char*)d_ws;
    auto alloc = [&](size_t bytes) {
        char* p = w;
        w += (bytes + 255) & ~(size_t)255;
        return p;
    };
    int*  col  = (int*)alloc((size_t)E * 4);            // 6.4 MB
    int*  rp   = (int*)alloc((size_t)(N + 1) * 4);      // 0.4 MB
    bf16* h1   = (bf16*)alloc((size_t)N * 128 * 2);     // 25.6 MB
    bf16* xbf  = (bf16*)alloc((size_t)N * 128 * 2);     // 25.6 MB (reused as h2)
    bf16* aggb = (bf16*)alloc((size_t)N * 128 * 2);     // 25.6 MB
    bf16* wsw1 = (bf16*)alloc(32768 * 2);               // 64 KB
    bf16* wsw2 = (bf16*)alloc(32768 * 2);
    bf16* wsw3 = (bf16*)alloc(32768 * 2);
    bf16* h2   = xbf;       // layer-2 output overwrites xbf (last read: layer-1 gemm)
    // CSR-build scratch aliases buffers written only AFTER the build completes:
    int*  T    = (int*)h1;                  // NB*GB ints (~306 KB) in h1's space
    int*  bsum = (int*)(h1 + 1024 * 1024);  // scan partials, past T
    int*  ebuf = (int*)aggb;                // E ints (6.4 MB) in aggb's space

    const int NB = (N + BSZ - 1) / BSZ;        // 391 buckets
    const int GB = (E + CHUNK - 1) / CHUNK;    // 196 sort blocks
    const int nT = NB * GB;                    // 76,636
    const int scanTBlocks = (nT + 255) / 256;  // 300 <= 512

    const int gemmBlocks = (N + 127) / 128;              // 782
    // swizzled 8-node-chunk grids: 8 XCD lanes x 16 chunks x ceil(gemmBlocks/8)
    const int chunkBlocks = 8 * 16 * ((gemmBlocks + 7) / 8);   // 12544

    // prep (cvt + wsw) and bhist: independent work, one dispatch
    prep_bhist_kernel<<<chunkBlocks + 48 + GB, 256, 0, stream>>>(
        x, xbf, N, chunkBlocks,
        w_rel1, w_root1, w_rel2, w_root2, w_rel3, w_root3,
        wsw1, wsw2, wsw3,
        dst, T, E, NB, GB);

    // CSR by dst: two-level counting sort (scan3 folded into consumers)
    scan1_kernel<<<scanTBlocks, 256, 0, stream>>>(T, T, bsum, nT);
    scan2_kernel<<<1, 512, 0, stream>>>(bsum, scanTBlocks);
    bscatter_kernel<<<GB, 256, 0, stream>>>(src, dst, T, bsum, ebuf, E, NB, GB);
    bbuild_kernel<<<NB, 256, 0, stream>>>(T, bsum, ebuf, rp, col, E, N, NB, GB);

    // layer 1
    agg_kernel<<<chunkBlocks, 512, 0, stream>>>(xbf, rp, col, aggb, N);
    mfma_gemm_kernel<true, bf16><<<gemmBlocks, 512, 0, stream>>>(aggb, xbf, wsw1, b1, h1, N);
    // layer 2
    agg_kernel<<<chunkBlocks, 512, 0, stream>>>(h1, rp, col, aggb, N);
    mfma_gemm_kernel<true, bf16><<<gemmBlocks, 512, 0, stream>>>(aggb, h1, wsw2, b2, h2, N);
    // layer 3
    agg_kernel<<<chunkBlocks, 512, 0, stream>>>(h2, rp, col, aggb, N);
    mfma_gemm_kernel<false, float><<<gemmBlocks, 512, 0, stream>>>(aggb, h2, wsw3, b3, out, N);
}